// Round 8
// baseline (414.450 us; speedup 1.0000x reference)
//
#include <hip/hip_runtime.h>

#define N_ATOMS 20000
#define N_EDGES 80000
#define ATOM_DIM 29
#define BOND_DIM 11
#define UNITS 64
#define STEPS 4
#define GCOLS 768      // 12*64 (11 bond slices + 1 plain-sum slice)
#define KTOT  832      // 768 (G) + 64 (h)
#define NCOLS 256      // 4 comps x 64 units
#define ASTRIDE 836    // f16; 418 dwords == 2 (mod 32) -> 4-way max on b128 reads
#define BM 32
#define NTH 512
#define CAP 320        // LDS edge-prefetch capacity (mean 128, sigma ~11 -> never exceeded)

typedef _Float16 f16;
typedef __attribute__((ext_vector_type(8))) _Float16 f16x8;
typedef __attribute__((ext_vector_type(4))) float f32x4;

__global__ void init_h(const float* __restrict__ atom, float* __restrict__ h,
                       f16* __restrict__ h16) {
    int idx = blockIdx.x*256 + threadIdx.x;
    if (idx >= N_ATOMS*UNITS) return;
    int a = idx >> 6, i = idx & 63;
    float v = (i < ATOM_DIM) ? atom[a*ATOM_DIM + i] : 0.f;
    h[idx] = v;
    h16[idx] = (f16)v;
}

// row_ptr[a] = first edge index with src >= a (edges sorted by src)
__global__ void build_rowptr(const int* __restrict__ pair, int* __restrict__ row_ptr) {
    int e = blockIdx.x*256 + threadIdx.x;
    if (e >= N_EDGES) return;
    int s = pair[2*e];
    if (e == 0) for (int a = 0; a <= s; a++) row_ptr[a] = 0;
    int snext = (e == N_EDGES-1) ? N_ATOMS : pair[2*(e+1)];
    for (int a = s+1; a <= snext; a++) row_ptr[a] = e+1;
}

// W3T[c][k] (f16, 256 x 832), c = comp*64+i, comp: 0=zsum 1=rsum 2=xh 3=rh.
// k<768 (k=b*64+q): sum_m E[k,m]*W2top[m,c], E[k,m]=ek[b,m*64+q] (b<11) or eb[m*64+q].
// k>=768 (j=k-768): W2bot[j,c] from grk. Also bias2[c] (f32) from gb.
__global__ void build_w3t(const float* __restrict__ ek, const float* __restrict__ eb,
                          const float* __restrict__ gk, const float* __restrict__ grk,
                          const float* __restrict__ gb, f16* __restrict__ W3T,
                          float* __restrict__ bias2) {
    int idx = blockIdx.x*256 + threadIdx.x;
    if (idx >= NCOLS*KTOT) return;
    int c = idx & 255, k = idx >> 8;
    int comp = c >> 6, i = c & 63;
    if (k == 0) {
        float b;
        if (comp == 0)      b = gb[i]       + gb[192 + i];
        else if (comp == 1) b = gb[64 + i]  + gb[192 + 64 + i];
        else if (comp == 2) b = gb[128 + i];
        else                b = gb[192 + 128 + i];
        bias2[c] = b;
    }
    float val = 0.f;
    if (k < GCOLS) {
        if (comp != 3) {
            int b = k >> 6, q = k & 63;
            const float* E = (b < BOND_DIM) ? (ek + (size_t)b*4096 + q) : (eb + q);
            const float* T = gk + comp*64 + i;
            #pragma unroll 8
            for (int m = 0; m < 64; m++) val += E[m*64] * T[m*192];
        }
    } else {
        int j = k - GCOLS;
        if (comp == 0)      val = grk[j*192 + i];
        else if (comp == 1) val = grk[j*192 + 64 + i];
        else if (comp == 3) val = grk[j*192 + 128 + i];
    }
    W3T[(size_t)c*KTOT + k] = (f16)val;
}

// Fused step, 512 threads / 8 waves, BM=32 atoms.
// phase 0: cooperative edge prefetch (dst, bond) -> LDS
// phase 1: gather -> A-tile [G | h] (32 x 832 f16) in LDS; wave owns 4 atoms
// phase 2: gates = A @ W3T^T, barrier-free MFMA K-loop (B from L2 direct)
// phase 3: GRU epilogue -> h, h16_out
__global__ __launch_bounds__(NTH) void fused_step(
    const int* __restrict__ pair, const int* __restrict__ row_ptr,
    const float* __restrict__ bond, const f16* __restrict__ h16_in,
    f16* __restrict__ h16_out, const f16* __restrict__ W3T,
    const float* __restrict__ bias2, float* __restrict__ h) {
  __shared__ f16 As[BM][ASTRIDE];      // 53.5 KB
  __shared__ int edst[CAP];            // 1.3 KB
  __shared__ float ebond[CAP][12];     // 15.4 KB
  int a0 = blockIdx.x * BM;
  int tid = threadIdx.x;
  int lane = tid & 63, w = tid >> 6;   // 8 waves
  int lq = lane >> 4, lr = lane & 15;

  int blk_start = row_ptr[a0];
  int blk_end   = row_ptr[a0 + BM];
  int ncap = min(blk_end - blk_start, CAP);

  // ---------- phase 0: edge prefetch (coalesced, fully parallel)
  for (int idx = tid; idx < ncap; idx += NTH)
    edst[idx] = pair[2*(blk_start + idx) + 1];
  for (int idx = tid; idx < ncap*BOND_DIM; idx += NTH) {
    int e = idx / BOND_DIM;
    ebond[e][idx - e*BOND_DIM] = bond[(size_t)blk_start*BOND_DIM + idx];
  }
  __syncthreads();

  // ---------- phase 1: gather; wave w owns atoms w*4 .. w*4+3, lane = h-col
  for (int t = 0; t < 4; t++) {
    int r = w*4 + t;
    int a = a0 + r;
    int s = row_ptr[a], e_end = row_ptr[a+1];
    float g[BOND_DIM+1];
    #pragma unroll
    for (int b=0;b<=BOND_DIM;b++) g[b] = 0.f;

    int e = s;
    for (; e + 1 < e_end; e += 2) {
      int le0 = e - blk_start, le1 = le0 + 1;
      if (le1 < CAP) {
        int d0 = edst[le0], d1 = edst[le1];
        float h0 = (float)h16_in[(size_t)d0*UNITS + lane];
        float h1 = (float)h16_in[(size_t)d1*UNITS + lane];
        g[BOND_DIM] += h0 + h1;
        #pragma unroll
        for (int b=0;b<BOND_DIM;b++)
          g[b] += ebond[le0][b]*h0 + ebond[le1][b]*h1;
      } else {  // overflow fallback (practically never taken)
        int d0 = pair[2*e+1], d1 = pair[2*e+3];
        float h0 = (float)h16_in[(size_t)d0*UNITS + lane];
        float h1 = (float)h16_in[(size_t)d1*UNITS + lane];
        g[BOND_DIM] += h0 + h1;
        #pragma unroll
        for (int b=0;b<BOND_DIM;b++)
          g[b] += bond[(size_t)e*BOND_DIM + b]*h0 + bond[(size_t)(e+1)*BOND_DIM + b]*h1;
      }
    }
    if (e < e_end) {
      int le0 = e - blk_start;
      int d0 = (le0 < CAP) ? edst[le0] : pair[2*e+1];
      float h0 = (float)h16_in[(size_t)d0*UNITS + lane];
      g[BOND_DIM] += h0;
      if (le0 < CAP) {
        #pragma unroll
        for (int b=0;b<BOND_DIM;b++) g[b] += ebond[le0][b]*h0;
      } else {
        #pragma unroll
        for (int b=0;b<BOND_DIM;b++) g[b] += bond[(size_t)e*BOND_DIM + b]*h0;
      }
    }
    #pragma unroll
    for (int b=0;b<=BOND_DIM;b++) As[r][b*64 + lane] = (f16)g[b];
    As[r][GCOLS + lane] = h16_in[(size_t)a*UNITS + lane];
  }

  // wave decomposition for GEMM/epilogue: mt = row-tile, cg = col-group (i-range)
  int mt = w >> 2, cg = w & 3;
  int i = cg*16 + lr;

  // prefetch epilogue operands (hide under K-loop)
  float bz  = bias2[i];
  float br  = bias2[64 + i];
  float bh  = bias2[128 + i];
  float brh = bias2[192 + i];
  float hold[4];
  #pragma unroll
  for (int rr=0;rr<4;rr++)
    hold[rr] = h[(size_t)(a0 + mt*16 + lq*4 + rr)*UNITS + i];

  __syncthreads();

  // ---------- phase 2: barrier-free MFMA K-loop
  f32x4 acc[4];
  #pragma unroll
  for (int n=0;n<4;n++) acc[n] = (f32x4){0.f,0.f,0.f,0.f};

  const f16* bp0 = W3T + (size_t)(0*64 + i)*KTOT + lq*8;
  const f16* bp1 = W3T + (size_t)(1*64 + i)*KTOT + lq*8;
  const f16* bp2 = W3T + (size_t)(2*64 + i)*KTOT + lq*8;
  const f16* bp3 = W3T + (size_t)(3*64 + i)*KTOT + lq*8;

  #pragma unroll 2
  for (int kt = 0; kt < KTOT/32; kt++) {
    f16x8 af  = *(const f16x8*)&As[mt*16 + lr][kt*32 + lq*8];
    f16x8 bf0 = *(const f16x8*)&bp0[kt*32];
    f16x8 bf1 = *(const f16x8*)&bp1[kt*32];
    f16x8 bf2 = *(const f16x8*)&bp2[kt*32];
    f16x8 bf3 = *(const f16x8*)&bp3[kt*32];
    acc[0] = __builtin_amdgcn_mfma_f32_16x16x32_f16(af, bf0, acc[0], 0, 0, 0);
    acc[1] = __builtin_amdgcn_mfma_f32_16x16x32_f16(af, bf1, acc[1], 0, 0, 0);
    acc[2] = __builtin_amdgcn_mfma_f32_16x16x32_f16(af, bf2, acc[2], 0, 0, 0);
    acc[3] = __builtin_amdgcn_mfma_f32_16x16x32_f16(af, bf3, acc[3], 0, 0, 0);
  }

  // ---------- phase 3: GRU epilogue (lane-local)
  #pragma unroll
  for (int rr=0;rr<4;rr++) {
    int a = a0 + mt*16 + lq*4 + rr;
    float zs = acc[0][rr] + bz;
    float rs = acc[1][rr] + br;
    float xh = acc[2][rr] + bh;
    float rh = acc[3][rr] + brh;
    float z  = 1.f/(1.f + __expf(-zs));
    float rg = 1.f/(1.f + __expf(-rs));
    float hh = tanhf(xh + rg*rh);
    float hn = z*hold[rr] + (1.f - z)*hh;
    h[(size_t)a*UNITS + i] = hn;
    h16_out[(size_t)a*UNITS + i] = (f16)hn;
  }
}

extern "C" void kernel_launch(void* const* d_in, const int* in_sizes, int n_in,
                              void* d_out, int out_size, void* d_ws, size_t ws_size,
                              hipStream_t stream) {
  const float* atom  = (const float*)d_in[0];
  const float* bond  = (const float*)d_in[1];
  const int*   pair  = (const int*)d_in[2];
  const float* ek    = (const float*)d_in[3];
  const float* eb    = (const float*)d_in[4];
  const float* gk    = (const float*)d_in[5];
  const float* grk   = (const float*)d_in[6];
  const float* gbias = (const float*)d_in[7];

  float* h = (float*)d_out;                          // 20000x64 fp32

  char* w = (char*)d_ws;
  int*   row_ptr = (int*)w;        w += 80032;                    // 20004 ints, 16B-pad
  f16*   h16a    = (f16*)w;        w += (size_t)N_ATOMS*UNITS*2;
  f16*   h16b    = (f16*)w;        w += (size_t)N_ATOMS*UNITS*2;
  f16*   W3T     = (f16*)w;        w += (size_t)NCOLS*KTOT*2;
  float* bias2   = (float*)w;      w += (size_t)256*4;

  init_h<<<(N_ATOMS*UNITS+255)/256, 256, 0, stream>>>(atom, h, h16a);
  build_rowptr<<<(N_EDGES+255)/256, 256, 0, stream>>>(pair, row_ptr);
  build_w3t<<<(NCOLS*KTOT+255)/256, 256, 0, stream>>>(ek, eb, gk, grk, gbias, W3T, bias2);

  f16* bufs[2] = { h16a, h16b };
  for (int s=0; s<STEPS; s++) {
    fused_step<<<N_ATOMS/BM, NTH, 0, stream>>>(
        pair, row_ptr, bond, bufs[s & 1], bufs[(s+1) & 1], W3T, bias2, h);
  }
}

// Round 9
// 288.628 us; speedup vs baseline: 1.4359x; 1.4359x over previous
//
#include <hip/hip_runtime.h>

#define N_ATOMS 20000
#define N_EDGES 80000
#define ATOM_DIM 29
#define BOND_DIM 11
#define UNITS 64
#define STEPS 4
#define GCOLS 768      // 12*64 (11 bond slices + 1 plain-sum slice)
#define KTOT  832      // 768 (G) + 64 (h)
#define BM    80       // atoms per block; 250 * 80 = 20000 exactly
#define NTH   512      // 8 waves
#define ASTRIDE 836    // f16 row stride of A-tile
#define CT_MAIN 12     // main col-tiles (N=192: z,r,xh)
#define KT_MAIN 26     // K=832
#define CT_RH 4        // rh col-tiles (N=64)
#define KT_RH 2        // K=64 (h only)
#define GSTRIDE 193    // gates f32 row stride
#define RSTRIDE 65     // rh f32 row stride

typedef _Float16 f16;
typedef __attribute__((ext_vector_type(8))) _Float16 f16x8;
typedef __attribute__((ext_vector_type(4))) float f32x4;

__global__ void init_h(const float* __restrict__ atom, float* __restrict__ h,
                       f16* __restrict__ h16) {
    int idx = blockIdx.x*256 + threadIdx.x;
    if (idx >= N_ATOMS*UNITS) return;
    int a = idx >> 6, i = idx & 63;
    float v = (i < ATOM_DIM) ? atom[a*ATOM_DIM + i] : 0.f;
    h[idx] = v;
    h16[idx] = (f16)v;
}

// row_ptr[a] = first edge index with src >= a (edges sorted by src)
__global__ void build_rowptr(const int* __restrict__ pair, int* __restrict__ row_ptr) {
    int e = blockIdx.x*256 + threadIdx.x;
    if (e >= N_EDGES) return;
    int s = pair[2*e];
    if (e == 0) for (int a = 0; a <= s; a++) row_ptr[a] = 0;
    int snext = (e == N_EDGES-1) ? N_ATOMS : pair[2*(e+1)];
    for (int a = s+1; a <= snext; a++) row_ptr[a] = e+1;
}

// W3m: tile-major [ct][kt][lane][8] f16; tile (ct,kt) holds B-frag for
// cols ct*16+lr (0..191 = z|r|xh), k = kt*32+lq*8+e. One wave-load = 1KB contig.
// col comp: 0=zsum 1=rsum 2=xh. k<768: (EKT2 @ gk_comp); k>=768: grk (comp<2) else 0.
// Also writes bias2[256] = [bz|br|bxh|brh].
__global__ void build_w3m(const float* __restrict__ ek, const float* __restrict__ eb,
                          const float* __restrict__ gk, const float* __restrict__ grk,
                          const float* __restrict__ gb, f16* __restrict__ W3m,
                          float* __restrict__ bias2) {
    int idx = blockIdx.x*256 + threadIdx.x;
    if (idx < 256) {
        int comp = idx >> 6, i = idx & 63;
        float b;
        if (comp == 0)      b = gb[i]       + gb[192 + i];
        else if (comp == 1) b = gb[64 + i]  + gb[256 + i];
        else if (comp == 2) b = gb[128 + i];
        else                b = gb[320 + i];
        bias2[idx] = b;
    }
    if (idx >= CT_MAIN*KT_MAIN*512) return;
    int t = idx >> 9, rem = idx & 511;
    int ct = t / KT_MAIN, kt = t % KT_MAIN;
    int lane = rem >> 3, e = rem & 7;
    int lq = lane >> 4, lr = lane & 15;
    int col = ct*16 + lr;           // 0..191
    int comp = col >> 6, i = col & 63;
    int k = kt*32 + lq*8 + e;       // 0..831
    float val = 0.f;
    if (k < GCOLS) {
        int b = k >> 6, q = k & 63;
        const float* E = (b < BOND_DIM) ? (ek + (size_t)b*4096 + q) : (eb + q);
        const float* T = gk + comp*64 + i;
        #pragma unroll 8
        for (int m = 0; m < 64; m++) val += E[m*64] * T[m*192];
    } else {
        int j = k - GCOLS;
        if (comp < 2) val = grk[j*192 + comp*64 + i];
        // comp==2 (xh): zero h-part
    }
    W3m[idx] = (f16)val;
}

// W3r: tile-major [rt][kt][lane][8]; cols i = rt*16+lr, k = j = kt*32+lq*8+e (h rows).
__global__ void build_w3r(const float* __restrict__ grk, f16* __restrict__ W3r) {
    int idx = blockIdx.x*256 + threadIdx.x;
    if (idx >= CT_RH*KT_RH*512) return;
    int t = idx >> 9, rem = idx & 511;
    int rt = t / KT_RH, kt = t % KT_RH;
    int lane = rem >> 3, e = rem & 7;
    int lq = lane >> 4, lr = lane & 15;
    int i = rt*16 + lr;
    int j = kt*32 + lq*8 + e;
    W3r[idx] = (f16)grk[j*192 + 128 + i];
}

// One fused step per 80-atom block (grid=250, 8 waves):
//  phase 1: gather -> A-tile [G | h] (80 x 832 f16) in LDS; wave owns 10 atoms
//  phase 2: waves 0-5: main GEMM (2 col-tiles each, 5 row-tiles, B contiguous 1KB loads)
//           waves 6-7: rh GEMM (K=64)
//  phase 3: acc -> LDS (reusing A-tile space), recombine, GRU epilogue -> h, h16_out
__global__ __launch_bounds__(NTH) void fused_step(
    const int* __restrict__ pair, const int* __restrict__ row_ptr,
    const float* __restrict__ bond, const f16* __restrict__ h16_in,
    f16* __restrict__ h16_out, const f16* __restrict__ W3m,
    const f16* __restrict__ W3r, const float* __restrict__ bias2,
    float* __restrict__ h) {
  __shared__ __align__(16) char smem[BM*ASTRIDE*2];          // 133,760 B
  f16 (*As)[ASTRIDE] = (f16 (*)[ASTRIDE])smem;
  float (*gates)[GSTRIDE] = (float (*)[GSTRIDE])smem;        // 61,760 B (reuse)
  float (*rhb)[RSTRIDE] = (float (*)[RSTRIDE])(smem + BM*GSTRIDE*4); // 20,800 B

  int a0 = blockIdx.x * BM;
  int tid = threadIdx.x;
  int lane = tid & 63, w = tid >> 6;
  int lq = lane >> 4, lr = lane & 15;

  // ---------- phase 1: gather; wave w owns atoms w*10 .. w*10+9, lane = h-col
  for (int t = 0; t < 10; t++) {
    int r = w*10 + t;
    int a = a0 + r;
    int s = row_ptr[a], e_end = row_ptr[a+1];
    float g[BOND_DIM+1];
    #pragma unroll
    for (int b=0;b<=BOND_DIM;b++) g[b] = 0.f;
    int e = s;
    for (; e + 1 < e_end; e += 2) {
      int d0 = pair[2*e+1], d1 = pair[2*e+3];
      float h0 = (float)h16_in[(size_t)d0*UNITS + lane];
      float h1 = (float)h16_in[(size_t)d1*UNITS + lane];
      g[BOND_DIM] += h0 + h1;
      #pragma unroll
      for (int b=0;b<BOND_DIM;b++)
        g[b] += bond[(size_t)e*BOND_DIM + b]*h0 + bond[(size_t)(e+1)*BOND_DIM + b]*h1;
    }
    if (e < e_end) {
      int d0 = pair[2*e+1];
      float h0 = (float)h16_in[(size_t)d0*UNITS + lane];
      g[BOND_DIM] += h0;
      #pragma unroll
      for (int b=0;b<BOND_DIM;b++) g[b] += bond[(size_t)e*BOND_DIM + b]*h0;
    }
    #pragma unroll
    for (int b=0;b<=BOND_DIM;b++) As[r][b*64 + lane] = (f16)g[b];
    As[r][GCOLS + lane] = h16_in[(size_t)a*UNITS + lane];
  }
  __syncthreads();

  // ---------- phase 2: GEMM (no B duplication across waves; 1KB coalesced B loads)
  f32x4 acc[5][2];
  #pragma unroll
  for (int m=0;m<5;m++) { acc[m][0]=(f32x4){0.f,0.f,0.f,0.f}; acc[m][1]=(f32x4){0.f,0.f,0.f,0.f}; }

  if (w < 6) {
    const f16* bp0 = W3m + ((size_t)(w*2    )*KT_MAIN)*512 + lane*8;
    const f16* bp1 = W3m + ((size_t)(w*2 + 1)*KT_MAIN)*512 + lane*8;
    for (int kt = 0; kt < KT_MAIN; kt++) {
      f16x8 bf0 = *(const f16x8*)(bp0 + (size_t)kt*512);
      f16x8 bf1 = *(const f16x8*)(bp1 + (size_t)kt*512);
      #pragma unroll
      for (int m=0;m<5;m++) {
        f16x8 af = *(const f16x8*)&As[m*16 + lr][kt*32 + lq*8];
        acc[m][0] = __builtin_amdgcn_mfma_f32_16x16x32_f16(af, bf0, acc[m][0], 0, 0, 0);
        acc[m][1] = __builtin_amdgcn_mfma_f32_16x16x32_f16(af, bf1, acc[m][1], 0, 0, 0);
      }
    }
  } else {
    int wr = w - 6;
    const f16* bp0 = W3r + ((size_t)(wr*2    )*KT_RH)*512 + lane*8;
    const f16* bp1 = W3r + ((size_t)(wr*2 + 1)*KT_RH)*512 + lane*8;
    for (int kt = 0; kt < KT_RH; kt++) {
      f16x8 bf0 = *(const f16x8*)(bp0 + (size_t)kt*512);
      f16x8 bf1 = *(const f16x8*)(bp1 + (size_t)kt*512);
      #pragma unroll
      for (int m=0;m<5;m++) {
        f16x8 af = *(const f16x8*)&As[m*16 + lr][GCOLS + kt*32 + lq*8];
        acc[m][0] = __builtin_amdgcn_mfma_f32_16x16x32_f16(af, bf0, acc[m][0], 0, 0, 0);
        acc[m][1] = __builtin_amdgcn_mfma_f32_16x16x32_f16(af, bf1, acc[m][1], 0, 0, 0);
      }
    }
  }
  __syncthreads();   // all As reads complete before overwrite

  // ---------- phase 3a: acc -> LDS (C/D layout: col=lane&15, row=lq*4+rr)
  if (w < 6) {
    #pragma unroll
    for (int m=0;m<5;m++)
      #pragma unroll
      for (int n=0;n<2;n++) {
        int col = (w*2+n)*16 + lr;
        #pragma unroll
        for (int rr=0;rr<4;rr++)
          gates[m*16 + lq*4 + rr][col] = acc[m][n][rr];
      }
  } else {
    int wr = w - 6;
    #pragma unroll
    for (int m=0;m<5;m++)
      #pragma unroll
      for (int n=0;n<2;n++) {
        int col = (wr*2+n)*16 + lr;
        #pragma unroll
        for (int rr=0;rr<4;rr++)
          rhb[m*16 + lq*4 + rr][col] = acc[m][n][rr];
      }
  }
  __syncthreads();

  // ---------- phase 3b: GRU epilogue; thread -> (a_loc = tid>>6 + p*8, i = tid&63)
  int i = tid & 63;
  float bz  = bias2[i];
  float br  = bias2[64 + i];
  float bxh = bias2[128 + i];
  float brh = bias2[192 + i];
  #pragma unroll
  for (int p=0;p<10;p++) {
    int a_loc = (tid >> 6) + p*8;
    int a = a0 + a_loc;
    float zs = gates[a_loc][i]        + bz;
    float rs = gates[a_loc][64 + i]   + br;
    float xh = gates[a_loc][128 + i]  + bxh;
    float rh = rhb[a_loc][i]          + brh;
    float z  = 1.f/(1.f + __expf(-zs));
    float rg = 1.f/(1.f + __expf(-rs));
    float hh = tanhf(xh + rg*rh);
    float hold = h[(size_t)a*UNITS + i];
    float hn = z*hold + (1.f - z)*hh;
    h[(size_t)a*UNITS + i] = hn;
    h16_out[(size_t)a*UNITS + i] = (f16)hn;
  }
}

extern "C" void kernel_launch(void* const* d_in, const int* in_sizes, int n_in,
                              void* d_out, int out_size, void* d_ws, size_t ws_size,
                              hipStream_t stream) {
  const float* atom  = (const float*)d_in[0];
  const float* bond  = (const float*)d_in[1];
  const int*   pair  = (const int*)d_in[2];
  const float* ek    = (const float*)d_in[3];
  const float* eb    = (const float*)d_in[4];
  const float* gk    = (const float*)d_in[5];
  const float* grk   = (const float*)d_in[6];
  const float* gbias = (const float*)d_in[7];

  float* h = (float*)d_out;                          // 20000x64 fp32

  char* w = (char*)d_ws;
  int*   row_ptr = (int*)w;        w += 80032;                          // 20004 ints
  f16*   h16a    = (f16*)w;        w += (size_t)N_ATOMS*UNITS*2;
  f16*   h16b    = (f16*)w;        w += (size_t)N_ATOMS*UNITS*2;
  f16*   W3m     = (f16*)w;        w += (size_t)CT_MAIN*KT_MAIN*512*2;  // 319,488 B
  f16*   W3r     = (f16*)w;        w += (size_t)CT_RH*KT_RH*512*2;      // 8,192 B
  float* bias2   = (float*)w;      w += (size_t)256*4;

  init_h<<<(N_ATOMS*UNITS+255)/256, 256, 0, stream>>>(atom, h, h16a);
  build_rowptr<<<(N_EDGES+255)/256, 256, 0, stream>>>(pair, row_ptr);
  build_w3m<<<(CT_MAIN*KT_MAIN*512+255)/256, 256, 0, stream>>>(ek, eb, gk, grk, gbias, W3m, bias2);
  build_w3r<<<(CT_RH*KT_RH*512+255)/256, 256, 0, stream>>>(grk, W3r);

  f16* bufs[2] = { h16a, h16b };
  for (int s=0; s<STEPS; s++) {
    fused_step<<<N_ATOMS/BM, NTH, 0, stream>>>(
        pair, row_ptr, bond, bufs[s & 1], bufs[(s+1) & 1], W3m, W3r, bias2, h);
  }
}

// Round 10
// 257.710 us; speedup vs baseline: 1.6082x; 1.1200x over previous
//
#include <hip/hip_runtime.h>

#define N_ATOMS 20000
#define N_EDGES 80000
#define ATOM_DIM 29
#define BOND_DIM 11
#define UNITS 64
#define STEPS 4
#define GCOLS 768      // 12*64 (11 bond slices + 1 plain-sum slice)
#define KTOT  832      // 768 (G) + 64 (h)
#define BM    32       // atoms per block; 625 * 32 = 20000 exactly
#define NTH   512      // 8 waves
#define ASTRIDE 836    // f16 row stride of A-tile (53,504 B -> 3 blocks/CU)
#define CT_MAIN 12     // main col-tiles (N=192: z,r,xh)
#define KT_MAIN 26     // K=832
#define CT_RH 4        // rh col-tiles (N=64)
#define KT_RH 2        // K=64 (h only)
#define GSTRIDE 193    // gates f32 row stride (overlay in As)
#define RSTRIDE 65     // rh f32 row stride (overlay in As)

typedef _Float16 f16;
typedef __attribute__((ext_vector_type(8))) _Float16 f16x8;
typedef __attribute__((ext_vector_type(4))) float f32x4;

__global__ void init_h(const float* __restrict__ atom, float* __restrict__ h,
                       f16* __restrict__ h16) {
    int idx = blockIdx.x*256 + threadIdx.x;
    if (idx >= N_ATOMS*UNITS) return;
    int a = idx >> 6, i = idx & 63;
    float v = (i < ATOM_DIM) ? atom[a*ATOM_DIM + i] : 0.f;
    h[idx] = v;
    h16[idx] = (f16)v;
}

// row_ptr[a] = first edge index with src >= a (edges sorted by src)
__global__ void build_rowptr(const int* __restrict__ pair, int* __restrict__ row_ptr) {
    int e = blockIdx.x*256 + threadIdx.x;
    if (e >= N_EDGES) return;
    int s = pair[2*e];
    if (e == 0) for (int a = 0; a <= s; a++) row_ptr[a] = 0;
    int snext = (e == N_EDGES-1) ? N_ATOMS : pair[2*(e+1)];
    for (int a = s+1; a <= snext; a++) row_ptr[a] = e+1;
}

// W3m: tile-major [ct][kt][lane][8] f16; tile (ct,kt) holds B-frag for
// cols ct*16+lr (0..191 = z|r|xh), k = kt*32+lq*8+e. One wave-load = 1KB contig.
// col comp: 0=zsum 1=rsum 2=xh. k<768: (EKT2 @ gk_comp); k>=768: grk (comp<2) else 0.
// Also writes bias2[256] = [bz|br|bxh|brh].
__global__ void build_w3m(const float* __restrict__ ek, const float* __restrict__ eb,
                          const float* __restrict__ gk, const float* __restrict__ grk,
                          const float* __restrict__ gb, f16* __restrict__ W3m,
                          float* __restrict__ bias2) {
    int idx = blockIdx.x*256 + threadIdx.x;
    if (idx < 256) {
        int comp = idx >> 6, i = idx & 63;
        float b;
        if (comp == 0)      b = gb[i]       + gb[192 + i];
        else if (comp == 1) b = gb[64 + i]  + gb[256 + i];
        else if (comp == 2) b = gb[128 + i];
        else                b = gb[320 + i];
        bias2[idx] = b;
    }
    if (idx >= CT_MAIN*KT_MAIN*512) return;
    int t = idx >> 9, rem = idx & 511;
    int ct = t / KT_MAIN, kt = t % KT_MAIN;
    int lane = rem >> 3, e = rem & 7;
    int lq = lane >> 4, lr = lane & 15;
    int col = ct*16 + lr;           // 0..191
    int comp = col >> 6, i = col & 63;
    int k = kt*32 + lq*8 + e;       // 0..831
    float val = 0.f;
    if (k < GCOLS) {
        int b = k >> 6, q = k & 63;
        const float* E = (b < BOND_DIM) ? (ek + (size_t)b*4096 + q) : (eb + q);
        const float* T = gk + comp*64 + i;
        #pragma unroll 8
        for (int m = 0; m < 64; m++) val += E[m*64] * T[m*192];
    } else {
        int j = k - GCOLS;
        if (comp < 2) val = grk[j*192 + comp*64 + i];
        // comp==2 (xh): zero h-part
    }
    W3m[idx] = (f16)val;
}

// W3r: tile-major [rt][kt][lane][8]; cols i = rt*16+lr, k = j = kt*32+lq*8+e (h rows).
__global__ void build_w3r(const float* __restrict__ grk, f16* __restrict__ W3r) {
    int idx = blockIdx.x*256 + threadIdx.x;
    if (idx >= CT_RH*KT_RH*512) return;
    int t = idx >> 9, rem = idx & 511;
    int rt = t / KT_RH, kt = t % KT_RH;
    int lane = rem >> 3, e = rem & 7;
    int lq = lane >> 4, lr = lane & 15;
    int i = rt*16 + lr;
    int j = kt*32 + lq*8 + e;
    W3r[idx] = (f16)grk[j*192 + 128 + i];
}

// One fused step per 32-atom block (grid=625, 8 waves, 3 blocks/CU):
//  phase 1: gather -> A-tile [G | h] (32 x 832 f16) in LDS; wave owns 4 atoms
//  phase 2: waves 0-5: main GEMM (2 col-tiles each, 2 row-tiles); waves 6-7: rh GEMM
//  phase 3: acc -> LDS overlay, recombine, GRU epilogue -> h, h16_out
__global__ __launch_bounds__(NTH, 6) void fused_step(
    const int* __restrict__ pair, const int* __restrict__ row_ptr,
    const float* __restrict__ bond, const f16* __restrict__ h16_in,
    f16* __restrict__ h16_out, const f16* __restrict__ W3m,
    const f16* __restrict__ W3r, const float* __restrict__ bias2,
    float* __restrict__ h) {
  __shared__ __align__(16) char smem[BM*ASTRIDE*2];          // 53,504 B
  f16 (*As)[ASTRIDE] = (f16 (*)[ASTRIDE])smem;
  float (*gates)[GSTRIDE] = (float (*)[GSTRIDE])smem;        // 24,704 B (overlay)
  float (*rhb)[RSTRIDE] = (float (*)[RSTRIDE])(smem + BM*GSTRIDE*4); // 8,320 B

  int a0 = blockIdx.x * BM;
  int tid = threadIdx.x;
  int lane = tid & 63, w = tid >> 6;
  int lq = lane >> 4, lr = lane & 15;

  // ---------- phase 1: gather; wave w owns atoms w*4 .. w*4+3, lane = h-col
  for (int t = 0; t < 4; t++) {
    int r = w*4 + t;
    int a = a0 + r;
    int s = row_ptr[a], e_end = row_ptr[a+1];
    float g[BOND_DIM+1];
    #pragma unroll
    for (int b=0;b<=BOND_DIM;b++) g[b] = 0.f;
    int e = s;
    for (; e + 1 < e_end; e += 2) {
      int d0 = pair[2*e+1], d1 = pair[2*e+3];
      float h0 = (float)h16_in[(size_t)d0*UNITS + lane];
      float h1 = (float)h16_in[(size_t)d1*UNITS + lane];
      g[BOND_DIM] += h0 + h1;
      #pragma unroll
      for (int b=0;b<BOND_DIM;b++)
        g[b] += bond[(size_t)e*BOND_DIM + b]*h0 + bond[(size_t)(e+1)*BOND_DIM + b]*h1;
    }
    if (e < e_end) {
      int d0 = pair[2*e+1];
      float h0 = (float)h16_in[(size_t)d0*UNITS + lane];
      g[BOND_DIM] += h0;
      #pragma unroll
      for (int b=0;b<BOND_DIM;b++) g[b] += bond[(size_t)e*BOND_DIM + b]*h0;
    }
    #pragma unroll
    for (int b=0;b<=BOND_DIM;b++) As[r][b*64 + lane] = (f16)g[b];
    As[r][GCOLS + lane] = h16_in[(size_t)a*UNITS + lane];
  }
  __syncthreads();

  // ---------- phase 2: GEMM (no B duplication across waves; 1KB coalesced B loads)
  f32x4 acc[2][2];
  #pragma unroll
  for (int m=0;m<2;m++) { acc[m][0]=(f32x4){0.f,0.f,0.f,0.f}; acc[m][1]=(f32x4){0.f,0.f,0.f,0.f}; }

  if (w < 6) {
    const f16* bp0 = W3m + ((size_t)(w*2    )*KT_MAIN)*512 + lane*8;
    const f16* bp1 = W3m + ((size_t)(w*2 + 1)*KT_MAIN)*512 + lane*8;
    #pragma unroll 2
    for (int kt = 0; kt < KT_MAIN; kt++) {
      f16x8 bf0 = *(const f16x8*)(bp0 + (size_t)kt*512);
      f16x8 bf1 = *(const f16x8*)(bp1 + (size_t)kt*512);
      #pragma unroll
      for (int m=0;m<2;m++) {
        f16x8 af = *(const f16x8*)&As[m*16 + lr][kt*32 + lq*8];
        acc[m][0] = __builtin_amdgcn_mfma_f32_16x16x32_f16(af, bf0, acc[m][0], 0, 0, 0);
        acc[m][1] = __builtin_amdgcn_mfma_f32_16x16x32_f16(af, bf1, acc[m][1], 0, 0, 0);
      }
    }
  } else {
    int wr = w - 6;
    const f16* bp0 = W3r + ((size_t)(wr*2    )*KT_RH)*512 + lane*8;
    const f16* bp1 = W3r + ((size_t)(wr*2 + 1)*KT_RH)*512 + lane*8;
    for (int kt = 0; kt < KT_RH; kt++) {
      f16x8 bf0 = *(const f16x8*)(bp0 + (size_t)kt*512);
      f16x8 bf1 = *(const f16x8*)(bp1 + (size_t)kt*512);
      #pragma unroll
      for (int m=0;m<2;m++) {
        f16x8 af = *(const f16x8*)&As[m*16 + lr][GCOLS + kt*32 + lq*8];
        acc[m][0] = __builtin_amdgcn_mfma_f32_16x16x32_f16(af, bf0, acc[m][0], 0, 0, 0);
        acc[m][1] = __builtin_amdgcn_mfma_f32_16x16x32_f16(af, bf1, acc[m][1], 0, 0, 0);
      }
    }
  }
  __syncthreads();   // all As reads complete before overwrite

  // ---------- phase 3a: acc -> LDS (C/D layout: col=lane&15, row=lq*4+rr)
  if (w < 6) {
    #pragma unroll
    for (int m=0;m<2;m++)
      #pragma unroll
      for (int n=0;n<2;n++) {
        int col = (w*2+n)*16 + lr;
        #pragma unroll
        for (int rr=0;rr<4;rr++)
          gates[m*16 + lq*4 + rr][col] = acc[m][n][rr];
      }
  } else {
    int wr = w - 6;
    #pragma unroll
    for (int m=0;m<2;m++)
      #pragma unroll
      for (int n=0;n<2;n++) {
        int col = (wr*2+n)*16 + lr;
        #pragma unroll
        for (int rr=0;rr<4;rr++)
          rhb[m*16 + lq*4 + rr][col] = acc[m][n][rr];
      }
  }
  __syncthreads();

  // ---------- phase 3b: GRU epilogue; thread -> (a_loc = tid>>6 + p*8, i = tid&63)
  int i = tid & 63;
  float bz  = bias2[i];
  float br  = bias2[64 + i];
  float bxh = bias2[128 + i];
  float brh = bias2[192 + i];
  #pragma unroll
  for (int p=0;p<4;p++) {
    int a_loc = (tid >> 6) + p*8;
    int a = a0 + a_loc;
    float zs = gates[a_loc][i]        + bz;
    float rs = gates[a_loc][64 + i]   + br;
    float xh = gates[a_loc][128 + i]  + bxh;
    float rh = rhb[a_loc][i]          + brh;
    float z  = 1.f/(1.f + __expf(-zs));
    float rg = 1.f/(1.f + __expf(-rs));
    float hh = tanhf(xh + rg*rh);
    float hold = h[(size_t)a*UNITS + i];
    float hn = z*hold + (1.f - z)*hh;
    h[(size_t)a*UNITS + i] = hn;
    h16_out[(size_t)a*UNITS + i] = (f16)hn;
  }
}

extern "C" void kernel_launch(void* const* d_in, const int* in_sizes, int n_in,
                              void* d_out, int out_size, void* d_ws, size_t ws_size,
                              hipStream_t stream) {
  const float* atom  = (const float*)d_in[0];
  const float* bond  = (const float*)d_in[1];
  const int*   pair  = (const int*)d_in[2];
  const float* ek    = (const float*)d_in[3];
  const float* eb    = (const float*)d_in[4];
  const float* gk    = (const float*)d_in[5];
  const float* grk   = (const float*)d_in[6];
  const float* gbias = (const float*)d_in[7];

  float* h = (float*)d_out;                          // 20000x64 fp32

  char* w = (char*)d_ws;
  int*   row_ptr = (int*)w;        w += 80032;                          // 20004 ints
  f16*   h16a    = (f16*)w;        w += (size_t)N_ATOMS*UNITS*2;
  f16*   h16b    = (f16*)w;        w += (size_t)N_ATOMS*UNITS*2;
  f16*   W3m     = (f16*)w;        w += (size_t)CT_MAIN*KT_MAIN*512*2;  // 319,488 B
  f16*   W3r     = (f16*)w;        w += (size_t)CT_RH*KT_RH*512*2;      // 8,192 B
  float* bias2   = (float*)w;      w += (size_t)256*4;

  init_h<<<(N_ATOMS*UNITS+255)/256, 256, 0, stream>>>(atom, h, h16a);
  build_rowptr<<<(N_EDGES+255)/256, 256, 0, stream>>>(pair, row_ptr);
  build_w3m<<<(CT_MAIN*KT_MAIN*512+255)/256, 256, 0, stream>>>(ek, eb, gk, grk, gbias, W3m, bias2);
  build_w3r<<<(CT_RH*KT_RH*512+255)/256, 256, 0, stream>>>(grk, W3r);

  f16* bufs[2] = { h16a, h16b };
  for (int s=0; s<STEPS; s++) {
    fused_step<<<N_ATOMS/BM, NTH, 0, stream>>>(
        pair, row_ptr, bond, bufs[s & 1], bufs[(s+1) & 1], W3m, W3r, bias2, h);
  }
}

// Round 11
// 194.713 us; speedup vs baseline: 2.1285x; 1.3235x over previous
//
#include <hip/hip_runtime.h>

#define N_ATOMS 20000
#define N_EDGES 80000
#define ATOM_DIM 29
#define BOND_DIM 11
#define UNITS 64
#define STEPS 4
#define GCOLS 768      // 12*64 (11 bond slices + 1 plain-sum slice)
#define KTOT  832      // 768 (G) + 64 (h)
#define BM    16       // atoms per block; 1250 * 16 = 20000 exactly
#define NTH   256      // 4 waves
#define ASTRIDE 836    // f16 row stride of A-tile (26,752 B -> 5+ blocks/CU)
#define CT_MAIN 12     // main col-tiles (N=192: z,r,xh)
#define KT_MAIN 26     // K=832
#define CT_RH 4        // rh col-tiles (N=64)
#define KT_RH 2        // K=64 (h only)
#define GSTRIDE 193    // gates f32 row stride (overlay in As)
#define RSTRIDE 65     // rh f32 row stride (overlay in As)

typedef _Float16 f16;
typedef __attribute__((ext_vector_type(8))) _Float16 f16x8;
typedef __attribute__((ext_vector_type(4))) float f32x4;

__global__ void init_h(const float* __restrict__ atom, float* __restrict__ h,
                       f16* __restrict__ h16) {
    int idx = blockIdx.x*256 + threadIdx.x;
    if (idx >= N_ATOMS*UNITS) return;
    int a = idx >> 6, i = idx & 63;
    float v = (i < ATOM_DIM) ? atom[a*ATOM_DIM + i] : 0.f;
    h[idx] = v;
    h16[idx] = (f16)v;
}

// row_ptr[a] = first edge index with src >= a (edges sorted by src)
__global__ void build_rowptr(const int* __restrict__ pair, int* __restrict__ row_ptr) {
    int e = blockIdx.x*256 + threadIdx.x;
    if (e >= N_EDGES) return;
    int s = pair[2*e];
    if (e == 0) for (int a = 0; a <= s; a++) row_ptr[a] = 0;
    int snext = (e == N_EDGES-1) ? N_ATOMS : pair[2*(e+1)];
    for (int a = s+1; a <= snext; a++) row_ptr[a] = e+1;
}

// W3m: tile-major [ct][kt][lane][8] f16; tile (ct,kt) holds B-frag for
// cols ct*16+lr (0..191 = z|r|xh), k = kt*32+lq*8+e. One wave-load = 1KB contig.
// col comp: 0=zsum 1=rsum 2=xh. k<768: (EKT2 @ gk_comp); k>=768: grk (comp<2) else 0.
// Also writes bias2[256] = [bz|br|bxh|brh].
__global__ void build_w3m(const float* __restrict__ ek, const float* __restrict__ eb,
                          const float* __restrict__ gk, const float* __restrict__ grk,
                          const float* __restrict__ gb, f16* __restrict__ W3m,
                          float* __restrict__ bias2) {
    int idx = blockIdx.x*256 + threadIdx.x;
    if (idx < 256) {
        int comp = idx >> 6, i = idx & 63;
        float b;
        if (comp == 0)      b = gb[i]       + gb[192 + i];
        else if (comp == 1) b = gb[64 + i]  + gb[256 + i];
        else if (comp == 2) b = gb[128 + i];
        else                b = gb[320 + i];
        bias2[idx] = b;
    }
    if (idx >= CT_MAIN*KT_MAIN*512) return;
    int t = idx >> 9, rem = idx & 511;
    int ct = t / KT_MAIN, kt = t % KT_MAIN;
    int lane = rem >> 3, e = rem & 7;
    int lq = lane >> 4, lr = lane & 15;
    int col = ct*16 + lr;           // 0..191
    int comp = col >> 6, i = col & 63;
    int k = kt*32 + lq*8 + e;       // 0..831
    float val = 0.f;
    if (k < GCOLS) {
        int b = k >> 6, q = k & 63;
        const float* E = (b < BOND_DIM) ? (ek + (size_t)b*4096 + q) : (eb + q);
        const float* T = gk + comp*64 + i;
        #pragma unroll 8
        for (int m = 0; m < 64; m++) val += E[m*64] * T[m*192];
    } else {
        int j = k - GCOLS;
        if (comp < 2) val = grk[j*192 + comp*64 + i];
        // comp==2 (xh): zero h-part
    }
    W3m[idx] = (f16)val;
}

// W3r: tile-major [rt][kt][lane][8]; cols i = rt*16+lr, k = j = kt*32+lq*8+e (h rows).
__global__ void build_w3r(const float* __restrict__ grk, f16* __restrict__ W3r) {
    int idx = blockIdx.x*256 + threadIdx.x;
    if (idx >= CT_RH*KT_RH*512) return;
    int t = idx >> 9, rem = idx & 511;
    int rt = t / KT_RH, kt = t % KT_RH;
    int lane = rem >> 3, e = rem & 7;
    int lq = lane >> 4, lr = lane & 15;
    int i = rt*16 + lr;
    int j = kt*32 + lq*8 + e;
    W3r[idx] = (f16)grk[j*192 + 128 + i];
}

// One fused step per 16-atom block (grid=1250, 4 waves, ~5 blocks/CU all-resident):
//  phase 0: issue B prefetch (depth 2) — latency hides under gather
//  phase 1: gather -> A-tile [G | h] (16 x 832 f16) in LDS; wave owns 4 atoms
//  phase 1b: prefetch epilogue operands (h rows, biases)
//  phase 2: waves 0-2: main GEMM (4 col-tiles each); wave 3: rh GEMM (K=64)
//           rolling register double-buffer on B, static indexing
//  phase 3: acc -> LDS overlay, recombine, GRU epilogue -> h, h16_out
__global__ __launch_bounds__(NTH, 5) void fused_step(
    const int* __restrict__ pair, const int* __restrict__ row_ptr,
    const float* __restrict__ bond, const f16* __restrict__ h16_in,
    f16* __restrict__ h16_out, const f16* __restrict__ W3m,
    const f16* __restrict__ W3r, const float* __restrict__ bias2,
    float* __restrict__ h) {
  __shared__ __align__(16) char smem[BM*ASTRIDE*2];          // 26,752 B
  f16 (*As)[ASTRIDE] = (f16 (*)[ASTRIDE])smem;
  float (*gates)[GSTRIDE] = (float (*)[GSTRIDE])smem;        // 12,352 B (overlay)
  float (*rhb)[RSTRIDE] = (float (*)[RSTRIDE])(smem + BM*GSTRIDE*4); // 4,160 B

  int a0 = blockIdx.x * BM;
  int tid = threadIdx.x;
  int lane = tid & 63, w = tid >> 6;
  int lq = lane >> 4, lr = lane & 15;

  // ---------- phase 0: B prefetch (depth 2 per stream), issued before gather
  const f16* bp[4];
  if (w < 3) {
    #pragma unroll
    for (int n=0;n<4;n++)
      bp[n] = W3m + ((size_t)(w*4 + n)*KT_MAIN)*512 + lane*8;
  } else {
    #pragma unroll
    for (int n=0;n<4;n++)
      bp[n] = W3r + ((size_t)n*KT_RH)*512 + lane*8;
  }
  f16x8 pb[4][2];
  #pragma unroll
  for (int n=0;n<4;n++) {
    pb[n][0] = *(const f16x8*)(bp[n]);
    pb[n][1] = *(const f16x8*)(bp[n] + 512);
  }

  // ---------- phase 1: gather; wave w owns atoms w*4 .. w*4+3, lane = h-col
  for (int t = 0; t < 4; t++) {
    int r = w*4 + t;
    int a = a0 + r;
    int s = row_ptr[a], e_end = row_ptr[a+1];
    float g[BOND_DIM+1];
    #pragma unroll
    for (int b=0;b<=BOND_DIM;b++) g[b] = 0.f;
    int e = s;
    for (; e + 1 < e_end; e += 2) {
      int d0 = pair[2*e+1], d1 = pair[2*e+3];
      float h0 = (float)h16_in[(size_t)d0*UNITS + lane];
      float h1 = (float)h16_in[(size_t)d1*UNITS + lane];
      g[BOND_DIM] += h0 + h1;
      #pragma unroll
      for (int b=0;b<BOND_DIM;b++)
        g[b] += bond[(size_t)e*BOND_DIM + b]*h0 + bond[(size_t)(e+1)*BOND_DIM + b]*h1;
    }
    if (e < e_end) {
      int d0 = pair[2*e+1];
      float h0 = (float)h16_in[(size_t)d0*UNITS + lane];
      g[BOND_DIM] += h0;
      #pragma unroll
      for (int b=0;b<BOND_DIM;b++) g[b] += bond[(size_t)e*BOND_DIM + b]*h0;
    }
    #pragma unroll
    for (int b=0;b<=BOND_DIM;b++) As[r][b*64 + lane] = (f16)g[b];
    As[r][GCOLS + lane] = h16_in[(size_t)a*UNITS + lane];
  }

  // ---------- phase 1b: prefetch epilogue operands (independent of GEMM)
  int ei = tid & 63;
  float bz  = bias2[ei];
  float br  = bias2[64 + ei];
  float bxh = bias2[128 + ei];
  float brh = bias2[192 + ei];
  float hold[4];
  #pragma unroll
  for (int p=0;p<4;p++)
    hold[p] = h[(size_t)(a0 + (tid >> 6) + p*4)*UNITS + ei];

  __syncthreads();

  // ---------- phase 2: GEMM, rolling register double-buffer on B
  f32x4 acc[4];
  #pragma unroll
  for (int n=0;n<4;n++) acc[n] = (f32x4){0.f,0.f,0.f,0.f};

  if (w < 3) {
    #pragma unroll 2
    for (int kt = 0; kt < KT_MAIN; kt++) {
      f16x8 af = *(const f16x8*)&As[lr][kt*32 + lq*8];
      acc[0] = __builtin_amdgcn_mfma_f32_16x16x32_f16(af, pb[0][kt&1], acc[0], 0, 0, 0);
      acc[1] = __builtin_amdgcn_mfma_f32_16x16x32_f16(af, pb[1][kt&1], acc[1], 0, 0, 0);
      acc[2] = __builtin_amdgcn_mfma_f32_16x16x32_f16(af, pb[2][kt&1], acc[2], 0, 0, 0);
      acc[3] = __builtin_amdgcn_mfma_f32_16x16x32_f16(af, pb[3][kt&1], acc[3], 0, 0, 0);
      if (kt + 2 < KT_MAIN) {
        #pragma unroll
        for (int n=0;n<4;n++)
          pb[n][kt&1] = *(const f16x8*)(bp[n] + (size_t)(kt+2)*512);
      }
    }
  } else {
    #pragma unroll
    for (int kt = 0; kt < KT_RH; kt++) {
      f16x8 af = *(const f16x8*)&As[lr][GCOLS + kt*32 + lq*8];
      acc[0] = __builtin_amdgcn_mfma_f32_16x16x32_f16(af, pb[0][kt], acc[0], 0, 0, 0);
      acc[1] = __builtin_amdgcn_mfma_f32_16x16x32_f16(af, pb[1][kt], acc[1], 0, 0, 0);
      acc[2] = __builtin_amdgcn_mfma_f32_16x16x32_f16(af, pb[2][kt], acc[2], 0, 0, 0);
      acc[3] = __builtin_amdgcn_mfma_f32_16x16x32_f16(af, pb[3][kt], acc[3], 0, 0, 0);
    }
  }
  __syncthreads();   // all As reads complete before overwrite

  // ---------- phase 3a: acc -> LDS (C/D layout: col=lane&15, row=lq*4+rr)
  if (w < 3) {
    #pragma unroll
    for (int n=0;n<4;n++) {
      int col = (w*4+n)*16 + lr;
      #pragma unroll
      for (int rr=0;rr<4;rr++)
        gates[lq*4 + rr][col] = acc[n][rr];
    }
  } else {
    #pragma unroll
    for (int n=0;n<4;n++) {
      int col = n*16 + lr;
      #pragma unroll
      for (int rr=0;rr<4;rr++)
        rhb[lq*4 + rr][col] = acc[n][rr];
    }
  }
  __syncthreads();

  // ---------- phase 3b: GRU epilogue; thread -> (a_loc = tid>>6 + p*4, i = tid&63)
  #pragma unroll
  for (int p=0;p<4;p++) {
    int a_loc = (tid >> 6) + p*4;
    int a = a0 + a_loc;
    float zs = gates[a_loc][ei]        + bz;
    float rs = gates[a_loc][64 + ei]   + br;
    float xh = gates[a_loc][128 + ei]  + bxh;
    float rh = rhb[a_loc][ei]          + brh;
    float z  = 1.f/(1.f + __expf(-zs));
    float rg = 1.f/(1.f + __expf(-rs));
    float hh = tanhf(xh + rg*rh);
    float hn = z*hold[p] + (1.f - z)*hh;
    h[(size_t)a*UNITS + ei] = hn;
    h16_out[(size_t)a*UNITS + ei] = (f16)hn;
  }
}

extern "C" void kernel_launch(void* const* d_in, const int* in_sizes, int n_in,
                              void* d_out, int out_size, void* d_ws, size_t ws_size,
                              hipStream_t stream) {
  const float* atom  = (const float*)d_in[0];
  const float* bond  = (const float*)d_in[1];
  const int*   pair  = (const int*)d_in[2];
  const float* ek    = (const float*)d_in[3];
  const float* eb    = (const float*)d_in[4];
  const float* gk    = (const float*)d_in[5];
  const float* grk   = (const float*)d_in[6];
  const float* gbias = (const float*)d_in[7];

  float* h = (float*)d_out;                          // 20000x64 fp32

  char* w = (char*)d_ws;
  int*   row_ptr = (int*)w;        w += 80032;                          // 20004 ints
  f16*   h16a    = (f16*)w;        w += (size_t)N_ATOMS*UNITS*2;
  f16*   h16b    = (f16*)w;        w += (size_t)N_ATOMS*UNITS*2;
  f16*   W3m     = (f16*)w;        w += (size_t)CT_MAIN*KT_MAIN*512*2;  // 319,488 B
  f16*   W3r     = (f16*)w;        w += (size_t)CT_RH*KT_RH*512*2;      // 8,192 B
  float* bias2   = (float*)w;      w += (size_t)256*4;

  init_h<<<(N_ATOMS*UNITS+255)/256, 256, 0, stream>>>(atom, h, h16a);
  build_rowptr<<<(N_EDGES+255)/256, 256, 0, stream>>>(pair, row_ptr);
  build_w3m<<<(CT_MAIN*KT_MAIN*512+255)/256, 256, 0, stream>>>(ek, eb, gk, grk, gbias, W3m, bias2);
  build_w3r<<<(CT_RH*KT_RH*512+255)/256, 256, 0, stream>>>(grk, W3r);

  f16* bufs[2] = { h16a, h16b };
  for (int s=0; s<STEPS; s++) {
    fused_step<<<N_ATOMS/BM, NTH, 0, stream>>>(
        pair, row_ptr, bond, bufs[s & 1], bufs[(s+1) & 1], W3m, W3r, bias2, h);
  }
}